// Round 1
// baseline (1661.193 us; speedup 1.0000x reference)
//
#include <hip/hip_runtime.h>
#include <hip/hip_bf16.h>
#include <stdint.h>

#define D_DIM 2048
#define N_STEPS 16384
#define B_BLK 1024
#define N_BLK (N_STEPS / B_BLK)       // 16
#define T_P (B_BLK / 128)             // 8 tiles per block dim
#define N_TILE (T_P * (T_P + 1) / 2)  // 36 lower tiles per block
#define ETA 0.01f
#define NWG 256

typedef __attribute__((ext_vector_type(8))) short short8_t;
typedef __attribute__((ext_vector_type(4))) float floatx4;

__device__ __forceinline__ short f2bf(float f) {
  __hip_bfloat16 h = __float2bfloat16(f);
  return __builtin_bit_cast(short, h);
}
__device__ __forceinline__ float bf2f(uint32_t bits) {
  return __builtin_bit_cast(float, bits << 16);
}

// ---------------------------------------------------------------------------
// Phase 1: block-local Gram matrices, lower tiles only.
// G_b[k][j] = <x_{b*B+k}, x_{b*B+j}>, stored bf16, tile-packed:
//   tile (ti,tj), tj<=ti, linear idx ti*(ti+1)/2+tj, each 128x128 row-major.
// ---------------------------------------------------------------------------
__global__ __launch_bounds__(256) void gram_kernel(const float* __restrict__ xs,
                                                   short* __restrict__ G) {
  int wg = blockIdx.x;
  int b = wg / N_TILE;
  int t = wg % N_TILE;
  int ti = 0;
  while ((ti + 1) * (ti + 2) / 2 <= t) ti++;
  int tj = t - ti * (ti + 1) / 2;

  __shared__ short As[128 * 72];  // 128 x 64 bf16, row stride 72 (pad: banks)
  __shared__ short Bs[128 * 72];

  int tid = threadIdx.x;
  int lane = tid & 63;
  int w = tid >> 6;       // wave 0..3 -> 2x2
  int wm = w >> 1, wn = w & 1;

  floatx4 acc[4][4];
  for (int i = 0; i < 4; i++)
    for (int j = 0; j < 4; j++)
      for (int r = 0; r < 4; r++) acc[i][j][r] = 0.f;

  const float* Arow = xs + (size_t)(b * B_BLK + ti * 128) * D_DIM;
  const float* Brow = xs + (size_t)(b * B_BLK + tj * 128) * D_DIM;
  bool diag = (ti == tj);

  for (int kk = 0; kk < D_DIM; kk += 64) {
    // stage A tile (and B tile if off-diagonal), fp32 -> bf16
    for (int i = 0; i < 8; i++) {
      int row = i * 16 + (tid >> 4);
      int c4 = (tid & 15) * 4;
      float4 av = *(const float4*)(Arow + (size_t)row * D_DIM + kk + c4);
      short4 as;
      as.x = f2bf(av.x); as.y = f2bf(av.y); as.z = f2bf(av.z); as.w = f2bf(av.w);
      *(short4*)(&As[row * 72 + c4]) = as;
      if (!diag) {
        float4 bv = *(const float4*)(Brow + (size_t)row * D_DIM + kk + c4);
        short4 bs;
        bs.x = f2bf(bv.x); bs.y = f2bf(bv.y); bs.z = f2bf(bv.z); bs.w = f2bf(bv.w);
        *(short4*)(&Bs[row * 72 + c4]) = bs;
      }
    }
    __syncthreads();

    const short* Bsrc = diag ? As : Bs;
    for (int ks = 0; ks < 64; ks += 32) {
      short8_t af[4], bfr[4];
      int quad = lane >> 4;
      int rr = lane & 15;
      int c = ks + quad * 8;
      for (int mt = 0; mt < 4; mt++) {
        int r = wm * 64 + mt * 16 + rr;
        af[mt] = *(const short8_t*)(&As[r * 72 + c]);
      }
      for (int nt = 0; nt < 4; nt++) {
        int r = wn * 64 + nt * 16 + rr;
        bfr[nt] = *(const short8_t*)(&Bsrc[r * 72 + c]);
      }
      for (int mt = 0; mt < 4; mt++)
        for (int nt = 0; nt < 4; nt++)
          acc[mt][nt] = __builtin_amdgcn_mfma_f32_16x16x32_bf16(
              af[mt], bfr[nt], acc[mt][nt], 0, 0, 0);
    }
    __syncthreads();
  }

  // epilogue: C/D layout col=lane&15, row=(lane>>4)*4+reg   [verified m89/m91]
  size_t gbase = ((size_t)(b * N_TILE + t)) * (128 * 128);
  int col0 = lane & 15;
  int row0 = (lane >> 4) * 4;
  for (int mt = 0; mt < 4; mt++)
    for (int nt = 0; nt < 4; nt++)
      for (int r = 0; r < 4; r++) {
        int row = wm * 64 + mt * 16 + row0 + r;
        int col = wn * 64 + nt * 16 + col0;
        G[gbase + (size_t)row * 128 + col] = f2bf(acc[mt][nt][r]);
      }
}

// ---------------------------------------------------------------------------
// Phase 2: sequential over blocks; per block: P-GEMV, 2 Jacobi sweeps of the
// triangular fixed point, theta update. Hand-rolled grid barrier (256 WGs on
// 256 CUs, block=256 -> trivially co-resident).
// ---------------------------------------------------------------------------
__device__ __forceinline__ void grid_barrier(int* ctr, int gen) {
  __syncthreads();
  if (threadIdx.x == 0) {
    __hip_atomic_fetch_add(ctr, 1, __ATOMIC_RELEASE, __HIP_MEMORY_SCOPE_AGENT);
    int target = gen * NWG;
    int guard = 0;
    while (__hip_atomic_load(ctr, __ATOMIC_ACQUIRE, __HIP_MEMORY_SCOPE_AGENT) <
               target &&
           guard < (1 << 20)) {
      guard++;
      __builtin_amdgcn_s_sleep(1);
    }
  }
  __syncthreads();
}

__device__ __forceinline__ float wave_reduce(float s) {
  for (int off = 32; off; off >>= 1) s += __shfl_xor(s, off, 64);
  return s;
}

__device__ __forceinline__ void sweep(const short* __restrict__ G,
                                      const float* __restrict__ P,
                                      const float* __restrict__ cin,
                                      float* __restrict__ cout, int b, int gw,
                                      int lane) {
  int k = gw;
  int ti = k >> 7, kr = k & 127;
  float s = 0.f;
  for (int tj = 0; tj <= ti; tj++) {
    size_t base = ((size_t)(b * N_TILE + ti * (ti + 1) / 2 + tj)) * (128 * 128) +
                  (size_t)kr * 128;
    uint32_t gv = *(const uint32_t*)(G + base + lane * 2);
    int jc = lane * 2;
    int lim = (tj == ti) ? kr : 128;
    int j0 = tj * 128 + jc;
    if (jc < lim) s += bf2f(gv & 0xffffu) * cin[j0];
    if (jc + 1 < lim) s += bf2f(gv >> 16) * cin[j0 + 1];
  }
  s = wave_reduce(s);
  if (lane == 0) {
    float p = P[k] + s;
    cout[k] = ETA / (1.f + __expf(p));
  }
}

__global__ __launch_bounds__(256, 1) void solve_kernel(
    const float* __restrict__ xs, const short* __restrict__ G,
    float* __restrict__ theta, float* __restrict__ P, float* __restrict__ c0,
    float* __restrict__ c1, float* __restrict__ c2, int* ctr) {
  int tid = threadIdx.x;
  int wg = blockIdx.x;
  int lane = tid & 63;
  int wid = tid >> 6;
  int gw = wg * 4 + wid;  // 0..1023 : one wave per block-row
  int gen = 0;

  for (int b = 0; b < N_BLK; b++) {
    // Phase A: P[k] = <x_k, theta>; c0[k] = f(P[k])
    {
      const float* xr = xs + (size_t)(b * B_BLK + gw) * D_DIM;
      float s = 0.f;
      for (int i = 0; i < D_DIM / 4; i += 64) {
        float4 xv = *(const float4*)(xr + (size_t)(i + lane) * 4);
        float4 tv = *(const float4*)(theta + (size_t)(i + lane) * 4);
        s += xv.x * tv.x + xv.y * tv.y + xv.z * tv.z + xv.w * tv.w;
      }
      s = wave_reduce(s);
      if (lane == 0) {
        P[gw] = s;
        c0[gw] = ETA / (1.f + __expf(s));
      }
    }
    grid_barrier(ctr, ++gen);

    sweep(G, P, c0, c1, b, gw, lane);   // Jacobi sweep 1
    grid_barrier(ctr, ++gen);
    sweep(G, P, c1, c2, b, gw, lane);   // Jacobi sweep 2 (safety)
    grid_barrier(ctr, ++gen);

    // Phase C: theta += X_b^T c2 (8 d-chunks x 32 k-chunks)
    {
      int dg = wg & 7, kg = wg >> 3;
      int d = dg * 256 + tid;
      int k0 = kg * 32;
      float s = 0.f;
      for (int k = k0; k < k0 + 32; k++) {
        s += c2[k] * xs[(size_t)(b * B_BLK + k) * D_DIM + d];
      }
      atomicAdd(&theta[d], s);
    }
    grid_barrier(ctr, ++gen);
  }
}

// ---------------------------------------------------------------------------
extern "C" void kernel_launch(void* const* d_in, const int* in_sizes, int n_in,
                              void* d_out, int out_size, void* d_ws,
                              size_t ws_size, hipStream_t stream) {
  const float* theta_in = (const float*)d_in[0];  // (2048,)
  const float* xs = (const float*)d_in[1];        // (16384, 2048)

  char* ws = (char*)d_ws;
  size_t gbytes = (size_t)N_BLK * N_TILE * 128 * 128 * sizeof(short);  // ~18.9MB
  short* G = (short*)ws;
  float* theta = (float*)(ws + gbytes);
  float* P = theta + D_DIM;
  float* c0 = P + B_BLK;
  float* c1 = c0 + B_BLK;
  float* c2 = c1 + B_BLK;
  int* ctr = (int*)(c2 + B_BLK);

  hipMemsetAsync(ctr, 0, 256, stream);
  hipMemcpyAsync(theta, theta_in, D_DIM * sizeof(float),
                 hipMemcpyDeviceToDevice, stream);

  gram_kernel<<<N_BLK * N_TILE, 256, 0, stream>>>(xs, G);
  solve_kernel<<<NWG, 256, 0, stream>>>(xs, G, theta, P, c0, c1, c2, ctr);

  hipMemcpyAsync(d_out, theta, D_DIM * sizeof(float), hipMemcpyDeviceToDevice,
                 stream);
}

// Round 2
// 1659.220 us; speedup vs baseline: 1.0012x; 1.0012x over previous
//
#include <hip/hip_runtime.h>
#include <hip/hip_bf16.h>
#include <stdint.h>

#define D_DIM 2048
#define N_STEPS 16384
#define B_BLK 1024
#define N_BLK (N_STEPS / B_BLK)       // 16
#define T_P (B_BLK / 128)             // 8 tiles per block dim
#define N_TILE (T_P * (T_P + 1) / 2)  // 36 lower tiles per block
#define ETA 0.01f
#define NWG 256
#define FLAG_STRIDE 16  // ints -> 64B per flag line

typedef __attribute__((ext_vector_type(8))) short short8_t;
typedef __attribute__((ext_vector_type(4))) float floatx4;

__device__ __forceinline__ short f2bf(float f) {
  __hip_bfloat16 h = __float2bfloat16(f);
  return __builtin_bit_cast(short, h);
}
__device__ __forceinline__ float bf2f(uint32_t bits) {
  return __builtin_bit_cast(float, bits << 16);
}

// ---------------------------------------------------------------------------
// Phase 0: cast xs (fp32) -> xb (bf16), one pass. 33.5M elems, 8 per thread.
// ---------------------------------------------------------------------------
__global__ __launch_bounds__(256) void cast_kernel(const float* __restrict__ xs,
                                                   short* __restrict__ xb) {
  size_t i = (size_t)blockIdx.x * 256 + threadIdx.x;  // one short8 per thread
  float4 a = ((const float4*)xs)[i * 2];
  float4 b = ((const float4*)xs)[i * 2 + 1];
  short8_t v;
  v[0] = f2bf(a.x); v[1] = f2bf(a.y); v[2] = f2bf(a.z); v[3] = f2bf(a.w);
  v[4] = f2bf(b.x); v[5] = f2bf(b.y); v[6] = f2bf(b.z); v[7] = f2bf(b.w);
  *(short8_t*)(xb + i * 8) = v;
}

// ---------------------------------------------------------------------------
// Phase 1: block-local Gram matrices (bf16 in, bf16 out), lower tiles only.
// ---------------------------------------------------------------------------
__global__ __launch_bounds__(256) void gram_kernel(const short* __restrict__ xb,
                                                   short* __restrict__ G) {
  int wg = blockIdx.x;
  int b = wg / N_TILE;
  int t = wg % N_TILE;
  int ti = 0;
  while ((ti + 1) * (ti + 2) / 2 <= t) ti++;
  int tj = t - ti * (ti + 1) / 2;

  __shared__ short As[128 * 72];  // 128 x 64 bf16, stride 72 (2-way banks: free)
  __shared__ short Bs[128 * 72];

  int tid = threadIdx.x;
  int lane = tid & 63;
  int w = tid >> 6;
  int wm = w >> 1, wn = w & 1;

  floatx4 acc[4][4];
  for (int i = 0; i < 4; i++)
    for (int j = 0; j < 4; j++)
      for (int r = 0; r < 4; r++) acc[i][j][r] = 0.f;

  const short* Arow = xb + (size_t)(b * B_BLK + ti * 128) * D_DIM;
  const short* Brow = xb + (size_t)(b * B_BLK + tj * 128) * D_DIM;
  bool diag = (ti == tj);

  for (int kk = 0; kk < D_DIM; kk += 64) {
    // stage: 128 rows x 64 cols bf16 = 16KB; 4 passes of 256 x short8
    for (int i = 0; i < 4; i++) {
      int row = i * 32 + (tid >> 3);
      int cg = (tid & 7) * 8;
      *(short8_t*)(&As[row * 72 + cg]) =
          *(const short8_t*)(Arow + (size_t)row * D_DIM + kk + cg);
      if (!diag)
        *(short8_t*)(&Bs[row * 72 + cg]) =
            *(const short8_t*)(Brow + (size_t)row * D_DIM + kk + cg);
    }
    __syncthreads();

    const short* Bsrc = diag ? As : Bs;
    for (int ks = 0; ks < 64; ks += 32) {
      short8_t af[4], bfr[4];
      int quad = lane >> 4;
      int rr = lane & 15;
      int c = ks + quad * 8;
      for (int mt = 0; mt < 4; mt++)
        af[mt] = *(const short8_t*)(&As[(wm * 64 + mt * 16 + rr) * 72 + c]);
      for (int nt = 0; nt < 4; nt++)
        bfr[nt] = *(const short8_t*)(&Bsrc[(wn * 64 + nt * 16 + rr) * 72 + c]);
      for (int mt = 0; mt < 4; mt++)
        for (int nt = 0; nt < 4; nt++)
          acc[mt][nt] = __builtin_amdgcn_mfma_f32_16x16x32_bf16(
              af[mt], bfr[nt], acc[mt][nt], 0, 0, 0);
    }
    __syncthreads();
  }

  // C/D layout: col=lane&15, row=(lane>>4)*4+reg  [verified m89/m91]
  size_t gbase = ((size_t)(b * N_TILE + t)) * (128 * 128);
  int col0 = lane & 15;
  int row0 = (lane >> 4) * 4;
  for (int mt = 0; mt < 4; mt++)
    for (int nt = 0; nt < 4; nt++)
      for (int r = 0; r < 4; r++) {
        int row = wm * 64 + mt * 16 + row0 + r;
        int col = wn * 64 + nt * 16 + col0;
        G[gbase + (size_t)row * 128 + col] = f2bf(acc[mt][nt][r]);
      }
}

// ---------------------------------------------------------------------------
// Flag-array grid barrier: no atomic RMWs. Each WG release-stores its own
// 64B-strided flag; WG0's threads poll one flag each; WG0 release-stores a
// single `release` word everyone else polls. Monotonic generations.
// ---------------------------------------------------------------------------
__device__ __forceinline__ void grid_barrier(int* flags, int* release, int gen,
                                             int wg, int tid) {
  __syncthreads();
  if (wg == 0) {
    if (tid > 0) {
      int guard = 0;
      while (__hip_atomic_load(&flags[tid * FLAG_STRIDE], __ATOMIC_ACQUIRE,
                               __HIP_MEMORY_SCOPE_AGENT) < gen &&
             guard < (1 << 20)) {
        guard++;
        __builtin_amdgcn_s_sleep(2);
      }
    }
    __syncthreads();
    if (tid == 0)
      __hip_atomic_store(release, gen, __ATOMIC_RELEASE,
                         __HIP_MEMORY_SCOPE_AGENT);
  } else {
    if (tid == 0) {
      __hip_atomic_store(&flags[wg * FLAG_STRIDE], gen, __ATOMIC_RELEASE,
                         __HIP_MEMORY_SCOPE_AGENT);
      int guard = 0;
      while (__hip_atomic_load(release, __ATOMIC_ACQUIRE,
                               __HIP_MEMORY_SCOPE_AGENT) < gen &&
             guard < (1 << 20)) {
        guard++;
        __builtin_amdgcn_s_sleep(2);
      }
    }
  }
  __syncthreads();
}

__device__ __forceinline__ float wave_reduce(float s) {
  for (int off = 32; off; off >>= 1) s += __shfl_xor(s, off, 64);
  return s;
}

// ---------------------------------------------------------------------------
// Phase 2: sequential over blocks. Per block (3 grid barriers):
//   A: P[k]=<x_k,theta>, c0=f(P)   | bar
//   S: c1 = f(P + tril(G)·c0)      | bar   (single Jacobi sweep)
//   C: theta += X_b^T c1           | bar
// ---------------------------------------------------------------------------
__global__ __launch_bounds__(256, 1) void solve_kernel(
    const short* __restrict__ xb, const short* __restrict__ G,
    float* __restrict__ theta, float* __restrict__ P, float* __restrict__ c0,
    float* __restrict__ c1, int* flags, int* release) {
  int tid = threadIdx.x;
  int wg = blockIdx.x;
  int lane = tid & 63;
  int wid = tid >> 6;
  int gw = wg * 4 + wid;  // 0..1023: one wave per step-row
  int gen = 0;

  __shared__ float red[4][64];

  for (int b = 0; b < N_BLK; b++) {
    // ---- Phase A: P[k] = <x_k, theta>; c0 = f(P)
    {
      const short* xr = xb + (size_t)(b * B_BLK + gw) * D_DIM;
      float s = 0.f;
      for (int i = 0; i < 4; i++) {
        int idx = (i * 64 + lane) * 8;
        short8_t xv = *(const short8_t*)(xr + idx);
        float4 t0 = *(const float4*)(theta + idx);
        float4 t1 = *(const float4*)(theta + idx + 4);
        s += bf2f((uint16_t)xv[0]) * t0.x + bf2f((uint16_t)xv[1]) * t0.y +
             bf2f((uint16_t)xv[2]) * t0.z + bf2f((uint16_t)xv[3]) * t0.w +
             bf2f((uint16_t)xv[4]) * t1.x + bf2f((uint16_t)xv[5]) * t1.y +
             bf2f((uint16_t)xv[6]) * t1.z + bf2f((uint16_t)xv[7]) * t1.w;
      }
      s = wave_reduce(s);
      if (lane == 0) {
        P[gw] = s;
        c0[gw] = ETA / (1.f + __expf(s));
      }
    }
    grid_barrier(flags, release, ++gen, wg, tid);

    // ---- Phase S: one Jacobi sweep: c1 = f(P + tril(G) c0)
    {
      int k = gw;
      int ti = k >> 7, kr = k & 127;
      float s = 0.f;
      for (int tj = 0; tj <= ti; tj++) {
        size_t base =
            ((size_t)(b * N_TILE + ti * (ti + 1) / 2 + tj)) * (128 * 128) +
            (size_t)kr * 128;
        uint32_t gv = *(const uint32_t*)(G + base + lane * 2);
        int jc = lane * 2;
        int lim = (tj == ti) ? kr : 128;
        int j0 = tj * 128 + jc;
        if (jc < lim) s += bf2f(gv & 0xffffu) * c0[j0];
        if (jc + 1 < lim) s += bf2f(gv >> 16) * c0[j0 + 1];
      }
      s = wave_reduce(s);
      if (lane == 0) {
        float p = P[k] + s;
        c1[k] = ETA / (1.f + __expf(p));
      }
    }
    grid_barrier(flags, release, ++gen, wg, tid);

    // ---- Phase C: theta += X_b^T c1.
    // WG (dg=wg&31, kg=wg>>5): d-slice of 64, k-range of 128.
    // 256 threads = 4 k-subranges (w) x 64 d (lane). LDS-reduce the 4
    // partials -> one atomicAdd per d per WG (8 adds/word total).
    {
      int dg = wg & 31, kg = wg >> 5;
      int d = dg * 64 + lane;
      int k0 = kg * 128 + wid * 32;
      float s = 0.f;
      for (int kk = 0; kk < 32; kk++) {
        int k = k0 + kk;
        s += c1[k] *
             bf2f((uint16_t)xb[(size_t)(b * B_BLK + k) * D_DIM + d]);
      }
      red[wid][lane] = s;
      __syncthreads();
      if (tid < 64) {
        float tot = red[0][tid] + red[1][tid] + red[2][tid] + red[3][tid];
        atomicAdd(&theta[dg * 64 + tid], tot);
      }
    }
    grid_barrier(flags, release, ++gen, wg, tid);
  }
}

// ---------------------------------------------------------------------------
extern "C" void kernel_launch(void* const* d_in, const int* in_sizes, int n_in,
                              void* d_out, int out_size, void* d_ws,
                              size_t ws_size, hipStream_t stream) {
  const float* theta_in = (const float*)d_in[0];  // (2048,)
  const float* xs = (const float*)d_in[1];        // (16384, 2048) fp32

  char* ws = (char*)d_ws;
  const size_t XB_BYTES = (size_t)N_STEPS * D_DIM * sizeof(short);       // 64MB
  const size_t G_BYTES = (size_t)N_BLK * N_TILE * 128 * 128 * sizeof(short);
  short* xb = (short*)ws;
  short* G = (short*)(ws + XB_BYTES);
  float* theta = (float*)(ws + XB_BYTES + G_BYTES);
  float* P = theta + D_DIM;
  float* c0 = P + B_BLK;
  float* c1 = c0 + B_BLK;
  int* flags = (int*)(c1 + B_BLK);
  int* release = flags + NWG * FLAG_STRIDE;

  hipMemsetAsync(flags, 0, (NWG * FLAG_STRIDE + 16) * sizeof(int), stream);
  hipMemcpyAsync(theta, theta_in, D_DIM * sizeof(float),
                 hipMemcpyDeviceToDevice, stream);

  cast_kernel<<<(N_STEPS * D_DIM / 8) / 256, 256, 0, stream>>>(xs, xb);
  gram_kernel<<<N_BLK * N_TILE, 256, 0, stream>>>(xb, G);
  solve_kernel<<<NWG, 256, 0, stream>>>(xb, G, theta, P, c0, c1, flags,
                                        release);

  hipMemcpyAsync(d_out, theta, D_DIM * sizeof(float), hipMemcpyDeviceToDevice,
                 stream);
}

// Round 3
// 504.774 us; speedup vs baseline: 3.2910x; 3.2871x over previous
//
#include <hip/hip_runtime.h>
#include <hip/hip_bf16.h>
#include <stdint.h>

#define D_DIM 2048
#define N_STEPS 16384
#define B_BLK 1024
#define N_BLK (N_STEPS / B_BLK)       // 16
#define T_P (B_BLK / 128)             // 8 tiles per block dim
#define N_TILE (T_P * (T_P + 1) / 2)  // 36 lower tiles per block
#define ETA 0.01f
#define NWG 256
#define FLAG_STRIDE 16  // ints -> 64B per flag line

typedef __attribute__((ext_vector_type(8))) short short8_t;
typedef __attribute__((ext_vector_type(4))) float floatx4;

__device__ __forceinline__ short f2bf(float f) {
  __hip_bfloat16 h = __float2bfloat16(f);
  return __builtin_bit_cast(short, h);
}
__device__ __forceinline__ float bf2f(uint32_t bits) {
  return __builtin_bit_cast(float, bits << 16);
}

// Write-through store: relaxed agent-scope atomic -> global_store sc0 sc1.
// NO buffer_wbl2 (that's only emitted for release). Visible at MALL once
// vmcnt retires; __syncthreads() drains vmcnt.
__device__ __forceinline__ void store_wt(float* p, float v) {
  __hip_atomic_store(p, v, __ATOMIC_RELAXED, __HIP_MEMORY_SCOPE_AGENT);
}

// ---------------------------------------------------------------------------
// Phase 0: cast xs (fp32) -> xb (bf16), one pass.
// ---------------------------------------------------------------------------
__global__ __launch_bounds__(256) void cast_kernel(const float* __restrict__ xs,
                                                   short* __restrict__ xb) {
  size_t i = (size_t)blockIdx.x * 256 + threadIdx.x;
  float4 a = ((const float4*)xs)[i * 2];
  float4 b = ((const float4*)xs)[i * 2 + 1];
  short8_t v;
  v[0] = f2bf(a.x); v[1] = f2bf(a.y); v[2] = f2bf(a.z); v[3] = f2bf(a.w);
  v[4] = f2bf(b.x); v[5] = f2bf(b.y); v[6] = f2bf(b.z); v[7] = f2bf(b.w);
  *(short8_t*)(xb + i * 8) = v;
}

// ---------------------------------------------------------------------------
// Phase 1: block-local Gram matrices (bf16 in/out), lower tiles only.
// (unchanged from R2 — isolated variable this round is the barrier)
// ---------------------------------------------------------------------------
__global__ __launch_bounds__(256) void gram_kernel(const short* __restrict__ xb,
                                                   short* __restrict__ G) {
  int wg = blockIdx.x;
  int b = wg / N_TILE;
  int t = wg % N_TILE;
  int ti = 0;
  while ((ti + 1) * (ti + 2) / 2 <= t) ti++;
  int tj = t - ti * (ti + 1) / 2;

  __shared__ short As[128 * 72];
  __shared__ short Bs[128 * 72];

  int tid = threadIdx.x;
  int lane = tid & 63;
  int w = tid >> 6;
  int wm = w >> 1, wn = w & 1;

  floatx4 acc[4][4];
  for (int i = 0; i < 4; i++)
    for (int j = 0; j < 4; j++)
      for (int r = 0; r < 4; r++) acc[i][j][r] = 0.f;

  const short* Arow = xb + (size_t)(b * B_BLK + ti * 128) * D_DIM;
  const short* Brow = xb + (size_t)(b * B_BLK + tj * 128) * D_DIM;
  bool diag = (ti == tj);

  for (int kk = 0; kk < D_DIM; kk += 64) {
    for (int i = 0; i < 4; i++) {
      int row = i * 32 + (tid >> 3);
      int cg = (tid & 7) * 8;
      *(short8_t*)(&As[row * 72 + cg]) =
          *(const short8_t*)(Arow + (size_t)row * D_DIM + kk + cg);
      if (!diag)
        *(short8_t*)(&Bs[row * 72 + cg]) =
            *(const short8_t*)(Brow + (size_t)row * D_DIM + kk + cg);
    }
    __syncthreads();

    const short* Bsrc = diag ? As : Bs;
    for (int ks = 0; ks < 64; ks += 32) {
      short8_t af[4], bfr[4];
      int quad = lane >> 4;
      int rr = lane & 15;
      int c = ks + quad * 8;
      for (int mt = 0; mt < 4; mt++)
        af[mt] = *(const short8_t*)(&As[(wm * 64 + mt * 16 + rr) * 72 + c]);
      for (int nt = 0; nt < 4; nt++)
        bfr[nt] = *(const short8_t*)(&Bsrc[(wn * 64 + nt * 16 + rr) * 72 + c]);
      for (int mt = 0; mt < 4; mt++)
        for (int nt = 0; nt < 4; nt++)
          acc[mt][nt] = __builtin_amdgcn_mfma_f32_16x16x32_bf16(
              af[mt], bfr[nt], acc[mt][nt], 0, 0, 0);
    }
    __syncthreads();
  }

  size_t gbase = ((size_t)(b * N_TILE + t)) * (128 * 128);
  int col0 = lane & 15;
  int row0 = (lane >> 4) * 4;
  for (int mt = 0; mt < 4; mt++)
    for (int nt = 0; nt < 4; nt++)
      for (int r = 0; r < 4; r++) {
        int row = wm * 64 + mt * 16 + row0 + r;
        int col = wn * 64 + nt * 16 + col0;
        G[gbase + (size_t)row * 128 + col] = f2bf(acc[mt][nt][r]);
      }
}

// ---------------------------------------------------------------------------
// Flush-free grid barrier: relaxed (monotonic) agent atomics only -> plain
// sc0sc1 loads/stores, NO buffer_inv / buffer_wbl2. Data ordering comes from
// __syncthreads()'s vmcnt(0) drain of the producers' write-through stores.
// ---------------------------------------------------------------------------
__device__ __forceinline__ void grid_barrier(int* flags, int* release, int gen,
                                             int wg, int tid) {
  __syncthreads();  // drains vmcnt -> all sc0sc1 stores visible at MALL
  if (wg == 0) {
    if (tid > 0) {  // thread t polls WG t's flag (parallel, distinct lines)
      int guard = 0;
      while (__hip_atomic_load(&flags[tid * FLAG_STRIDE], __ATOMIC_RELAXED,
                               __HIP_MEMORY_SCOPE_AGENT) < gen &&
             guard < (1 << 20)) {
        guard++;
        __builtin_amdgcn_s_sleep(1);
      }
    }
    __syncthreads();
    if (tid == 0)
      __hip_atomic_store(release, gen, __ATOMIC_RELAXED,
                         __HIP_MEMORY_SCOPE_AGENT);
  } else {
    if (tid == 0) {
      __hip_atomic_store(&flags[wg * FLAG_STRIDE], gen, __ATOMIC_RELAXED,
                         __HIP_MEMORY_SCOPE_AGENT);
      int guard = 0;
      while (__hip_atomic_load(release, __ATOMIC_RELAXED,
                               __HIP_MEMORY_SCOPE_AGENT) < gen &&
             guard < (1 << 20)) {
        guard++;
        __builtin_amdgcn_s_sleep(1);
      }
    }
  }
  asm volatile("" ::: "memory");  // no compiler hoist of data loads above poll
  __syncthreads();
}

__device__ __forceinline__ float wave_reduce(float s) {
  for (int off = 32; off; off >>= 1) s += __shfl_xor(s, off, 64);
  return s;
}

// ---------------------------------------------------------------------------
// Phase 2: sequential over blocks, 3 flush-free barriers per block.
// Buffers rotate per block so consumer reads are plain cached loads on
// never-before-touched addresses; producers store write-through (sc0sc1).
// ---------------------------------------------------------------------------
__global__ __launch_bounds__(256, 1) void solve_kernel(
    const short* __restrict__ xb, const short* __restrict__ G,
    float* __restrict__ theta_arr, float* __restrict__ c0_arr,
    float* __restrict__ c1_arr, int* flags, int* release) {
  int tid = threadIdx.x;
  int wg = blockIdx.x;
  int lane = tid & 63;
  int wid = tid >> 6;
  int gw = wg * 4 + wid;  // 0..1023: one wave per step-row
  int gen = 0;

  __shared__ float red[4][8];

  for (int b = 0; b < N_BLK; b++) {
    const float* theta = theta_arr + (size_t)b * D_DIM;  // rotated
    float* c0 = c0_arr + (size_t)b * B_BLK;
    float* c1 = c1_arr + (size_t)b * B_BLK;
    float p_k;

    // ---- Phase A: p_k = <x_gw, theta_b> (kept in registers); c0 = f(p)
    {
      const short* xr = xb + (size_t)(b * B_BLK + gw) * D_DIM;
      float s = 0.f;
#pragma unroll
      for (int i = 0; i < 4; i++) {
        int idx = (i * 64 + lane) * 8;
        short8_t xv = *(const short8_t*)(xr + idx);
        float4 t0 = *(const float4*)(theta + idx);
        float4 t1 = *(const float4*)(theta + idx + 4);
        s += bf2f((uint16_t)xv[0]) * t0.x + bf2f((uint16_t)xv[1]) * t0.y +
             bf2f((uint16_t)xv[2]) * t0.z + bf2f((uint16_t)xv[3]) * t0.w +
             bf2f((uint16_t)xv[4]) * t1.x + bf2f((uint16_t)xv[5]) * t1.y +
             bf2f((uint16_t)xv[6]) * t1.z + bf2f((uint16_t)xv[7]) * t1.w;
      }
      s = wave_reduce(s);  // butterfly: all lanes hold the sum
      p_k = s;
      if (lane == 0) store_wt(&c0[gw], ETA / (1.f + __expf(s)));
    }
    grid_barrier(flags, release, ++gen, wg, tid);

    // ---- Phase S: c1[k] = f(p_k + tril(G_b)[k,:] . c0)
    {
      int ti = gw >> 7, kr = gw & 127;
      float s = 0.f;
      for (int tj = 0; tj <= ti; tj++) {
        size_t base =
            ((size_t)(b * N_TILE + ti * (ti + 1) / 2 + tj)) * (128 * 128) +
            (size_t)kr * 128;
        uint32_t gv = *(const uint32_t*)(G + base + lane * 2);
        int jc = lane * 2;
        int lim = (tj == ti) ? kr : 128;
        int j0 = tj * 128 + jc;
        if (jc < lim) s += bf2f(gv & 0xffffu) * c0[j0];
        if (jc + 1 < lim) s += bf2f(gv >> 16) * c0[j0 + 1];
      }
      s = wave_reduce(s);
      if (lane == 0) store_wt(&c1[gw], ETA / (1.f + __expf(p_k + s)));
    }
    grid_barrier(flags, release, ++gen, wg, tid);

    // ---- Phase C: theta_{b+1}[d] = theta_b[d] + sum_k c1[k] xb[k][d]
    // Single-writer: WG wg owns d in [wg*8, wg*8+8). Thread tid sums k in
    // [tid*4, tid*4+4) for all 8 d's (short8 = contiguous 16B per row).
    {
      int k0 = tid * 4;
      float4 cv = *(const float4*)(c1 + k0);
      const short* xp = xb + (size_t)(b * B_BLK + k0) * D_DIM + wg * 8;
      float a8[8] = {0.f, 0.f, 0.f, 0.f, 0.f, 0.f, 0.f, 0.f};
#pragma unroll
      for (int kq = 0; kq < 4; kq++) {
        short8_t xv = *(const short8_t*)(xp + (size_t)kq * D_DIM);
        float c = (kq == 0) ? cv.x : (kq == 1) ? cv.y : (kq == 2) ? cv.z : cv.w;
#pragma unroll
        for (int j = 0; j < 8; j++) a8[j] += c * bf2f((uint16_t)xv[j]);
      }
#pragma unroll
      for (int j = 0; j < 8; j++) a8[j] = wave_reduce(a8[j]);
      if (lane == 0) {
#pragma unroll
        for (int j = 0; j < 8; j++) red[wid][j] = a8[j];
      }
      __syncthreads();
      if (tid < 8) {
        float tot = red[0][tid] + red[1][tid] + red[2][tid] + red[3][tid];
        store_wt(&theta_arr[(size_t)(b + 1) * D_DIM + wg * 8 + tid],
                 theta[wg * 8 + tid] + tot);
      }
    }
    if (b < N_BLK - 1) grid_barrier(flags, release, ++gen, wg, tid);
  }
}

// ---------------------------------------------------------------------------
extern "C" void kernel_launch(void* const* d_in, const int* in_sizes, int n_in,
                              void* d_out, int out_size, void* d_ws,
                              size_t ws_size, hipStream_t stream) {
  const float* theta_in = (const float*)d_in[0];  // (2048,)
  const float* xs = (const float*)d_in[1];        // (16384, 2048) fp32

  char* ws = (char*)d_ws;
  const size_t XB_BYTES = (size_t)N_STEPS * D_DIM * sizeof(short);  // 64MB
  const size_t G_BYTES = (size_t)N_BLK * N_TILE * 128 * 128 * sizeof(short);
  short* xb = (short*)ws;
  short* G = (short*)(ws + XB_BYTES);
  float* theta_arr = (float*)(ws + XB_BYTES + G_BYTES);  // (N_BLK+1) x 2048
  float* c0_arr = theta_arr + (size_t)(N_BLK + 1) * D_DIM;  // N_BLK x 1024
  float* c1_arr = c0_arr + (size_t)N_BLK * B_BLK;
  int* flags = (int*)(c1_arr + (size_t)N_BLK * B_BLK);
  int* release = flags + NWG * FLAG_STRIDE;

  hipMemsetAsync(flags, 0, (NWG * FLAG_STRIDE + 16) * sizeof(int), stream);
  hipMemcpyAsync(theta_arr, theta_in, D_DIM * sizeof(float),
                 hipMemcpyDeviceToDevice, stream);

  cast_kernel<<<(N_STEPS * D_DIM / 8) / 256, 256, 0, stream>>>(xs, xb);
  gram_kernel<<<N_BLK * N_TILE, 256, 0, stream>>>(xb, G);
  solve_kernel<<<NWG, 256, 0, stream>>>(xb, G, theta_arr, c0_arr, c1_arr,
                                        flags, release);

  hipMemcpyAsync(d_out, theta_arr + (size_t)N_BLK * D_DIM,
                 D_DIM * sizeof(float), hipMemcpyDeviceToDevice, stream);
}

// Round 4
// 475.068 us; speedup vs baseline: 3.4967x; 1.0625x over previous
//
#include <hip/hip_runtime.h>
#include <hip/hip_bf16.h>
#include <stdint.h>

#define D_DIM 2048
#define N_STEPS 16384
#define B_BLK 1024
#define N_BLK (N_STEPS / B_BLK)       // 16
#define T_P (B_BLK / 128)             // 8 tiles per block dim
#define N_TILE (T_P * (T_P + 1) / 2)  // 36 lower tiles per block
#define ETA 0.01f
#define NWG 256
#define FLAG_STRIDE 16  // ints -> 64B per flag line

typedef __attribute__((ext_vector_type(8))) short short8_t;
typedef __attribute__((ext_vector_type(4))) float floatx4;

__device__ __forceinline__ short f2bf(float f) {
  __hip_bfloat16 h = __float2bfloat16(f);
  return __builtin_bit_cast(short, h);
}
__device__ __forceinline__ float bf2f(uint32_t bits) {
  return __builtin_bit_cast(float, bits << 16);
}

// Write-through store (relaxed agent atomic -> global_store sc0 sc1, no cache
// flush). Visible at MALL once vmcnt retires; __syncthreads drains vmcnt.
__device__ __forceinline__ void store_wt(float* p, float v) {
  __hip_atomic_store(p, v, __ATOMIC_RELAXED, __HIP_MEMORY_SCOPE_AGENT);
}

// Async global->LDS, 16B per lane. LDS dest must be lane-linear (uniform
// base + lane*16) — our chunk index is tid-linear, satisfying this.
__device__ __forceinline__ void gl_lds16(const short* g, short* l) {
  __builtin_amdgcn_global_load_lds(
      (const __attribute__((address_space(1))) void*)g,
      (__attribute__((address_space(3))) void*)l, 16, 0, 0);
}

// ---------------------------------------------------------------------------
// Phase 0: cast xs (fp32) -> xb (bf16), one pass.
// ---------------------------------------------------------------------------
__global__ __launch_bounds__(256) void cast_kernel(const float* __restrict__ xs,
                                                   short* __restrict__ xb) {
  size_t i = (size_t)blockIdx.x * 256 + threadIdx.x;
  float4 a = ((const float4*)xs)[i * 2];
  float4 b = ((const float4*)xs)[i * 2 + 1];
  short8_t v;
  v[0] = f2bf(a.x); v[1] = f2bf(a.y); v[2] = f2bf(a.z); v[3] = f2bf(a.w);
  v[4] = f2bf(b.x); v[5] = f2bf(b.y); v[6] = f2bf(b.z); v[7] = f2bf(b.w);
  *(short8_t*)(xb + i * 8) = v;
}

// ---------------------------------------------------------------------------
// Phase 1: block-local Gram tiles, m97-style: global_load_lds 16B staging
// into flat (no-pad) LDS with XOR column swizzle. LDS row r, 16B-slot s
// holds global column-chunk (s ^ (r&7)) -> ds_read_b128 fragment reads hit
// each bank 2-way (free) instead of 16-way.
// ---------------------------------------------------------------------------
__global__ __launch_bounds__(256) void gram_kernel(const short* __restrict__ xb,
                                                   short* __restrict__ G) {
  int wg = blockIdx.x;
  int b = wg / N_TILE;
  int t = wg % N_TILE;
  int ti = 0;
  while ((ti + 1) * (ti + 2) / 2 <= t) ti++;
  int tj = t - ti * (ti + 1) / 2;

  __shared__ short As[128 * 64];
  __shared__ short Bs[128 * 64];

  int tid = threadIdx.x;
  int lane = tid & 63;
  int w = tid >> 6;
  int wm = w >> 1, wn = w & 1;
  int quad = lane >> 4, rr = lane & 15;

  floatx4 acc[4][4];
#pragma unroll
  for (int i = 0; i < 4; i++)
#pragma unroll
    for (int j = 0; j < 4; j++)
#pragma unroll
      for (int r = 0; r < 4; r++) acc[i][j][r] = 0.f;

  const short* Arow = xb + (size_t)(b * B_BLK + ti * 128) * D_DIM;
  const short* Brow = xb + (size_t)(b * B_BLK + tj * 128) * D_DIM;
  bool diag = (ti == tj);

  for (int kk = 0; kk < D_DIM; kk += 64) {
#pragma unroll
    for (int tch = 0; tch < 4; tch++) {
      int chunk = tch * 256 + tid;  // 1024 x 16B chunks = 128x64 bf16
      int row = chunk >> 3, slot = chunk & 7;
      int cc = slot ^ (row & 7);  // swizzle
      gl_lds16(Arow + (size_t)row * D_DIM + kk + cc * 8, &As[chunk * 8]);
      if (!diag)
        gl_lds16(Brow + (size_t)row * D_DIM + kk + cc * 8, &Bs[chunk * 8]);
    }
    __syncthreads();  // drains vmcnt -> LDS staging complete

    const short* Bsrc = diag ? As : Bs;
#pragma unroll
    for (int ks = 0; ks < 2; ks++) {  // k-offsets 0, 32
      short8_t af[4], bfr[4];
#pragma unroll
      for (int mt = 0; mt < 4; mt++) {
        int r = wm * 64 + mt * 16 + rr;
        int slot = (ks * 4 + quad) ^ (r & 7);
        af[mt] = *(const short8_t*)(&As[r * 64 + slot * 8]);
      }
#pragma unroll
      for (int nt = 0; nt < 4; nt++) {
        int r = wn * 64 + nt * 16 + rr;
        int slot = (ks * 4 + quad) ^ (r & 7);
        bfr[nt] = *(const short8_t*)(&Bsrc[r * 64 + slot * 8]);
      }
#pragma unroll
      for (int mt = 0; mt < 4; mt++)
#pragma unroll
        for (int nt = 0; nt < 4; nt++)
          acc[mt][nt] = __builtin_amdgcn_mfma_f32_16x16x32_bf16(
              af[mt], bfr[nt], acc[mt][nt], 0, 0, 0);
    }
    __syncthreads();
  }

  // C/D layout: col=lane&15, row=(lane>>4)*4+reg  [verified m89/m91]
  size_t gbase = ((size_t)(b * N_TILE + t)) * (128 * 128);
  int col0 = lane & 15;
  int row0 = (lane >> 4) * 4;
#pragma unroll
  for (int mt = 0; mt < 4; mt++)
#pragma unroll
    for (int nt = 0; nt < 4; nt++)
#pragma unroll
      for (int r = 0; r < 4; r++) {
        int row = wm * 64 + mt * 16 + row0 + r;
        int col = wn * 64 + nt * 16 + col0;
        G[gbase + (size_t)row * 128 + col] = f2bf(acc[mt][nt][r]);
      }
}

// ---------------------------------------------------------------------------
// Flush-free grid barrier (relaxed agent atomics only; see R3 notes).
// ---------------------------------------------------------------------------
__device__ __forceinline__ void grid_barrier(int* flags, int* release, int gen,
                                             int wg, int tid) {
  __syncthreads();
  if (wg == 0) {
    if (tid > 0) {
      int guard = 0;
      while (__hip_atomic_load(&flags[tid * FLAG_STRIDE], __ATOMIC_RELAXED,
                               __HIP_MEMORY_SCOPE_AGENT) < gen &&
             guard < (1 << 20)) {
        guard++;
        __builtin_amdgcn_s_sleep(1);
      }
    }
    __syncthreads();
    if (tid == 0)
      __hip_atomic_store(release, gen, __ATOMIC_RELAXED,
                         __HIP_MEMORY_SCOPE_AGENT);
  } else {
    if (tid == 0) {
      __hip_atomic_store(&flags[wg * FLAG_STRIDE], gen, __ATOMIC_RELAXED,
                         __HIP_MEMORY_SCOPE_AGENT);
      int guard = 0;
      while (__hip_atomic_load(release, __ATOMIC_RELAXED,
                               __HIP_MEMORY_SCOPE_AGENT) < gen &&
             guard < (1 << 20)) {
        guard++;
        __builtin_amdgcn_s_sleep(1);
      }
    }
  }
  asm volatile("" ::: "memory");
  __syncthreads();
}

__device__ __forceinline__ float wave_reduce(float s) {
  for (int off = 32; off; off >>= 1) s += __shfl_xor(s, off, 64);
  return s;
}

// ---------------------------------------------------------------------------
// Phase 2: sequential over blocks, 3 flush-free barriers per block.
// ---------------------------------------------------------------------------
__global__ __launch_bounds__(256, 1) void solve_kernel(
    const short* __restrict__ xb, const short* __restrict__ G,
    float* __restrict__ theta_arr, float* __restrict__ c0_arr,
    float* __restrict__ c1_arr, int* flags, int* release) {
  int tid = threadIdx.x;
  int wg = blockIdx.x;
  int lane = tid & 63;
  int wid = tid >> 6;
  int gw = wg * 4 + wid;  // 0..1023: one wave per step-row
  int gen = 0;

  __shared__ float c1s[B_BLK];      // 4 KB
  __shared__ float redc[4][4][8];   // wave x d-octet x elem

  for (int b = 0; b < N_BLK; b++) {
    const float* theta = theta_arr + (size_t)b * D_DIM;  // rotated
    float* c0 = c0_arr + (size_t)b * B_BLK;
    float* c1 = c1_arr + (size_t)b * B_BLK;
    float p_k;

    // ---- Phase A: p_k = <x_gw, theta_b> (registers); c0 = f(p)
    {
      const short* xr = xb + (size_t)(b * B_BLK + gw) * D_DIM;
      float s = 0.f;
#pragma unroll
      for (int i = 0; i < 4; i++) {
        int idx = (i * 64 + lane) * 8;
        short8_t xv = *(const short8_t*)(xr + idx);
        float4 t0 = *(const float4*)(theta + idx);
        float4 t1 = *(const float4*)(theta + idx + 4);
        s += bf2f((uint16_t)xv[0]) * t0.x + bf2f((uint16_t)xv[1]) * t0.y +
             bf2f((uint16_t)xv[2]) * t0.z + bf2f((uint16_t)xv[3]) * t0.w +
             bf2f((uint16_t)xv[4]) * t1.x + bf2f((uint16_t)xv[5]) * t1.y +
             bf2f((uint16_t)xv[6]) * t1.z + bf2f((uint16_t)xv[7]) * t1.w;
      }
      s = wave_reduce(s);
      p_k = s;
      if (lane == 0) store_wt(&c0[gw], ETA / (1.f + __expf(s)));
    }
    grid_barrier(flags, release, ++gen, wg, tid);

    // ---- Phase S: c1[k] = f(p_k + tril(G_b)[k,:] . c0)
    {
      int ti = gw >> 7, kr = gw & 127;
      float s = 0.f;
      for (int tj = 0; tj <= ti; tj++) {
        size_t base =
            ((size_t)(b * N_TILE + ti * (ti + 1) / 2 + tj)) * (128 * 128) +
            (size_t)kr * 128;
        uint32_t gv = *(const uint32_t*)(G + base + lane * 2);
        float2 cv = *(const float2*)(c0 + tj * 128 + lane * 2);
        int jc = lane * 2;
        int lim = (tj == ti) ? kr : 128;
        if (jc < lim) s += bf2f(gv & 0xffffu) * cv.x;
        if (jc + 1 < lim) s += bf2f(gv >> 16) * cv.y;
      }
      s = wave_reduce(s);
      if (lane == 0) store_wt(&c1[gw], ETA / (1.f + __expf(p_k + s)));
    }
    grid_barrier(flags, release, ++gen, wg, tid);

    // ---- Phase C: theta_{b+1}[d] = theta_b[d] + sum_k c1[k] xb[k][d]
    // 64 active WGs; WG wg owns d-slice [wg*32, wg*32+32) = one 64B line per
    // row -> coalesced, zero over-fetch, single-writer.
    if (wg < 64) {
#pragma unroll
      for (int i = 0; i < 4; i++) c1s[i * 256 + tid] = c1[i * 256 + tid];
      __syncthreads();
      int d0 = wg * 32;
      const short* xp =
          xb + (size_t)(b * B_BLK) * D_DIM + d0 + (lane & 3) * 8;
      float a8[8] = {0.f, 0.f, 0.f, 0.f, 0.f, 0.f, 0.f, 0.f};
      int rbase = wid * 256 + (lane >> 2);
      for (int i = 0; i < 16; i++) {
        int row = rbase + i * 16;
        short8_t xv = *(const short8_t*)(xp + (size_t)row * D_DIM);
        float c = c1s[row];
#pragma unroll
        for (int j = 0; j < 8; j++) a8[j] += c * bf2f((uint16_t)xv[j]);
      }
      // reduce across the 16 lanes sharing (lane&3)
#pragma unroll
      for (int off = 4; off < 64; off <<= 1)
#pragma unroll
        for (int j = 0; j < 8; j++) a8[j] += __shfl_xor(a8[j], off, 64);
      if (lane < 4) {
#pragma unroll
        for (int j = 0; j < 8; j++) redc[wid][lane][j] = a8[j];
      }
      __syncthreads();
      if (tid < 32) {
        int oct = tid >> 3, e = tid & 7;
        float tot = redc[0][oct][e] + redc[1][oct][e] + redc[2][oct][e] +
                    redc[3][oct][e];
        store_wt(&theta_arr[(size_t)(b + 1) * D_DIM + d0 + tid],
                 theta[d0 + tid] + tot);
      }
    }
    if (b < N_BLK - 1) grid_barrier(flags, release, ++gen, wg, tid);
  }
}

// ---------------------------------------------------------------------------
extern "C" void kernel_launch(void* const* d_in, const int* in_sizes, int n_in,
                              void* d_out, int out_size, void* d_ws,
                              size_t ws_size, hipStream_t stream) {
  const float* theta_in = (const float*)d_in[0];  // (2048,)
  const float* xs = (const float*)d_in[1];        // (16384, 2048) fp32

  char* ws = (char*)d_ws;
  const size_t XB_BYTES = (size_t)N_STEPS * D_DIM * sizeof(short);  // 64MB
  const size_t G_BYTES = (size_t)N_BLK * N_TILE * 128 * 128 * sizeof(short);
  short* xb = (short*)ws;
  short* G = (short*)(ws + XB_BYTES);
  float* theta_arr = (float*)(ws + XB_BYTES + G_BYTES);  // (N_BLK+1) x 2048
  float* c0_arr = theta_arr + (size_t)(N_BLK + 1) * D_DIM;
  float* c1_arr = c0_arr + (size_t)N_BLK * B_BLK;
  int* flags = (int*)(c1_arr + (size_t)N_BLK * B_BLK);
  int* release = flags + NWG * FLAG_STRIDE;

  hipMemsetAsync(flags, 0, (NWG * FLAG_STRIDE + 16) * sizeof(int), stream);
  hipMemcpyAsync(theta_arr, theta_in, D_DIM * sizeof(float),
                 hipMemcpyDeviceToDevice, stream);

  cast_kernel<<<(N_STEPS * D_DIM / 8) / 256, 256, 0, stream>>>(xs, xb);
  gram_kernel<<<N_BLK * N_TILE, 256, 0, stream>>>(xb, G);
  solve_kernel<<<NWG, 256, 0, stream>>>(xb, G, theta_arr, c0_arr, c1_arr,
                                        flags, release);

  hipMemcpyAsync(d_out, theta_arr + (size_t)N_BLK * D_DIM,
                 D_DIM * sizeof(float), hipMemcpyDeviceToDevice, stream);
}

// Round 5
// 438.668 us; speedup vs baseline: 3.7869x; 1.0830x over previous
//
#include <hip/hip_runtime.h>
#include <hip/hip_bf16.h>
#include <stdint.h>

#define D_DIM 2048
#define N_STEPS 16384
#define B_BLK 1024
#define N_BLK (N_STEPS / B_BLK)       // 16
#define T_P (B_BLK / 128)             // 8 tiles per block dim
#define N_TILE (T_P * (T_P + 1) / 2)  // 36 lower tiles per block
#define ETA 0.01f
#define NWG 256
#define FLAG_STRIDE 16  // ints -> 64B per flag line

typedef __attribute__((ext_vector_type(8))) short short8_t;
typedef __attribute__((ext_vector_type(4))) float floatx4;

__device__ __forceinline__ short f2bf(float f) {
  __hip_bfloat16 h = __float2bfloat16(f);
  return __builtin_bit_cast(short, h);
}
__device__ __forceinline__ float bf2f(uint32_t bits) {
  return __builtin_bit_cast(float, bits << 16);
}

// Write-through store (relaxed agent atomic -> global_store sc0 sc1, no cache
// flush). Visible at MALL once vmcnt retires; __syncthreads drains vmcnt.
__device__ __forceinline__ void store_wt(float* p, float v) {
  __hip_atomic_store(p, v, __ATOMIC_RELAXED, __HIP_MEMORY_SCOPE_AGENT);
}

// Async global->LDS, 16B per lane (lane-linear LDS dest).
__device__ __forceinline__ void gl_lds16(const short* g, short* l) {
  __builtin_amdgcn_global_load_lds(
      (const __attribute__((address_space(1))) void*)g,
      (__attribute__((address_space(3))) void*)l, 16, 0, 0);
}

// ---------------------------------------------------------------------------
// Phase 0: cast xs (fp32) -> xb (bf16), one pass.
// ---------------------------------------------------------------------------
__global__ __launch_bounds__(256) void cast_kernel(const float* __restrict__ xs,
                                                   short* __restrict__ xb) {
  size_t i = (size_t)blockIdx.x * 256 + threadIdx.x;
  float4 a = ((const float4*)xs)[i * 2];
  float4 b = ((const float4*)xs)[i * 2 + 1];
  short8_t v;
  v[0] = f2bf(a.x); v[1] = f2bf(a.y); v[2] = f2bf(a.z); v[3] = f2bf(a.w);
  v[4] = f2bf(b.x); v[5] = f2bf(b.y); v[6] = f2bf(b.z); v[7] = f2bf(b.w);
  *(short8_t*)(xb + i * 8) = v;
}

// ---------------------------------------------------------------------------
// Phase 1: block-local Gram tiles. R5 change: XCD-locality dispatch swizzle.
// Dispatch i -> XCD x=i&7 (blockIdx%8 heuristic) processes blocks {x, x+8}
// only, so each XCD's working set is one 4MB panel set that fits its 4MB L2.
// 576 = 8 XCDs x 72 WGs (36 tiles x 2 blocks).
// ---------------------------------------------------------------------------
__global__ __launch_bounds__(256) void gram_kernel(const short* __restrict__ xb,
                                                   short* __restrict__ G) {
  int i = blockIdx.x;
  int x = i & 7, j = i >> 3;  // x: XCD slot, j: 0..71
  int b = (j < 36) ? x : x + 8;
  int t = (j < 36) ? j : j - 36;
  int ti = 0;
  while ((ti + 1) * (ti + 2) / 2 <= t) ti++;
  int tj = t - ti * (ti + 1) / 2;

  __shared__ short As[128 * 64];
  __shared__ short Bs[128 * 64];

  int tid = threadIdx.x;
  int lane = tid & 63;
  int w = tid >> 6;
  int wm = w >> 1, wn = w & 1;
  int quad = lane >> 4, rr = lane & 15;

  floatx4 acc[4][4];
#pragma unroll
  for (int ii = 0; ii < 4; ii++)
#pragma unroll
    for (int jj = 0; jj < 4; jj++)
#pragma unroll
      for (int r = 0; r < 4; r++) acc[ii][jj][r] = 0.f;

  const short* Arow = xb + (size_t)(b * B_BLK + ti * 128) * D_DIM;
  const short* Brow = xb + (size_t)(b * B_BLK + tj * 128) * D_DIM;
  bool diag = (ti == tj);

  for (int kk = 0; kk < D_DIM; kk += 64) {
#pragma unroll
    for (int tch = 0; tch < 4; tch++) {
      int chunk = tch * 256 + tid;  // 1024 x 16B chunks = 128x64 bf16
      int row = chunk >> 3, slot = chunk & 7;
      int cc = slot ^ (row & 7);  // swizzle
      gl_lds16(Arow + (size_t)row * D_DIM + kk + cc * 8, &As[chunk * 8]);
      if (!diag)
        gl_lds16(Brow + (size_t)row * D_DIM + kk + cc * 8, &Bs[chunk * 8]);
    }
    __syncthreads();  // drains vmcnt -> LDS staging complete

    const short* Bsrc = diag ? As : Bs;
#pragma unroll
    for (int ks = 0; ks < 2; ks++) {  // k-offsets 0, 32
      short8_t af[4], bfr[4];
#pragma unroll
      for (int mt = 0; mt < 4; mt++) {
        int r = wm * 64 + mt * 16 + rr;
        int slot = (ks * 4 + quad) ^ (r & 7);
        af[mt] = *(const short8_t*)(&As[r * 64 + slot * 8]);
      }
#pragma unroll
      for (int nt = 0; nt < 4; nt++) {
        int r = wn * 64 + nt * 16 + rr;
        int slot = (ks * 4 + quad) ^ (r & 7);
        bfr[nt] = *(const short8_t*)(&Bsrc[r * 64 + slot * 8]);
      }
#pragma unroll
      for (int mt = 0; mt < 4; mt++)
#pragma unroll
        for (int nt = 0; nt < 4; nt++)
          acc[mt][nt] = __builtin_amdgcn_mfma_f32_16x16x32_bf16(
              af[mt], bfr[nt], acc[mt][nt], 0, 0, 0);
    }
    __syncthreads();
  }

  // C/D layout: col=lane&15, row=(lane>>4)*4+reg  [verified m89/m91]
  size_t gbase = ((size_t)(b * N_TILE + t)) * (128 * 128);
  int col0 = lane & 15;
  int row0 = (lane >> 4) * 4;
#pragma unroll
  for (int mt = 0; mt < 4; mt++)
#pragma unroll
    for (int nt = 0; nt < 4; nt++)
#pragma unroll
      for (int r = 0; r < 4; r++) {
        int row = wm * 64 + mt * 16 + row0 + r;
        int col = wn * 64 + nt * 16 + col0;
        G[gbase + (size_t)row * 128 + col] = f2bf(acc[mt][nt][r]);
      }
}

// ---------------------------------------------------------------------------
// Flush-free grid barrier (relaxed agent atomics only; see R3 notes).
// ---------------------------------------------------------------------------
__device__ __forceinline__ void grid_barrier(int* flags, int* release, int gen,
                                             int wg, int tid) {
  __syncthreads();
  if (wg == 0) {
    if (tid > 0) {
      int guard = 0;
      while (__hip_atomic_load(&flags[tid * FLAG_STRIDE], __ATOMIC_RELAXED,
                               __HIP_MEMORY_SCOPE_AGENT) < gen &&
             guard < (1 << 20)) {
        guard++;
        __builtin_amdgcn_s_sleep(1);
      }
    }
    __syncthreads();
    if (tid == 0)
      __hip_atomic_store(release, gen, __ATOMIC_RELAXED,
                         __HIP_MEMORY_SCOPE_AGENT);
  } else {
    if (tid == 0) {
      __hip_atomic_store(&flags[wg * FLAG_STRIDE], gen, __ATOMIC_RELAXED,
                         __HIP_MEMORY_SCOPE_AGENT);
      int guard = 0;
      while (__hip_atomic_load(release, __ATOMIC_RELAXED,
                               __HIP_MEMORY_SCOPE_AGENT) < gen &&
             guard < (1 << 20)) {
        guard++;
        __builtin_amdgcn_s_sleep(1);
      }
    }
  }
  asm volatile("" ::: "memory");
  __syncthreads();
}

__device__ __forceinline__ float wave_reduce(float s) {
  for (int off = 32; off; off >>= 1) s += __shfl_xor(s, off, 64);
  return s;
}

// ---------------------------------------------------------------------------
// Phase 2: sequential over blocks, 3 flush-free barriers per block.
// ---------------------------------------------------------------------------
__global__ __launch_bounds__(256, 1) void solve_kernel(
    const short* __restrict__ xb, const short* __restrict__ G,
    float* __restrict__ theta_arr, float* __restrict__ c0_arr,
    float* __restrict__ c1_arr, int* flags, int* release) {
  int tid = threadIdx.x;
  int wg = blockIdx.x;
  int lane = tid & 63;
  int wid = tid >> 6;
  int gw = wg * 4 + wid;  // 0..1023: one wave per step-row
  int gen = 0;

  __shared__ float c1s[B_BLK];      // 4 KB
  __shared__ float redc[4][4][8];   // wave x d-octet x elem

  for (int b = 0; b < N_BLK; b++) {
    const float* theta = theta_arr + (size_t)b * D_DIM;  // rotated
    float* c0 = c0_arr + (size_t)b * B_BLK;
    float* c1 = c1_arr + (size_t)b * B_BLK;
    float p_k;

    // ---- Phase A: p_k = <x_gw, theta_b> (registers); c0 = f(p)
    {
      const short* xr = xb + (size_t)(b * B_BLK + gw) * D_DIM;
      float s = 0.f;
#pragma unroll
      for (int i = 0; i < 4; i++) {
        int idx = (i * 64 + lane) * 8;
        short8_t xv = *(const short8_t*)(xr + idx);
        float4 t0 = *(const float4*)(theta + idx);
        float4 t1 = *(const float4*)(theta + idx + 4);
        s += bf2f((uint16_t)xv[0]) * t0.x + bf2f((uint16_t)xv[1]) * t0.y +
             bf2f((uint16_t)xv[2]) * t0.z + bf2f((uint16_t)xv[3]) * t0.w +
             bf2f((uint16_t)xv[4]) * t1.x + bf2f((uint16_t)xv[5]) * t1.y +
             bf2f((uint16_t)xv[6]) * t1.z + bf2f((uint16_t)xv[7]) * t1.w;
      }
      s = wave_reduce(s);
      p_k = s;
      if (lane == 0) store_wt(&c0[gw], ETA / (1.f + __expf(s)));
    }
    grid_barrier(flags, release, ++gen, wg, tid);

    // ---- Phase S: c1[k] = f(p_k + tril(G_b)[k,:] . c0)
    {
      int ti = gw >> 7, kr = gw & 127;
      float s = 0.f;
      for (int tj = 0; tj <= ti; tj++) {
        size_t base =
            ((size_t)(b * N_TILE + ti * (ti + 1) / 2 + tj)) * (128 * 128) +
            (size_t)kr * 128;
        uint32_t gv = *(const uint32_t*)(G + base + lane * 2);
        float2 cv = *(const float2*)(c0 + tj * 128 + lane * 2);
        int jc = lane * 2;
        int lim = (tj == ti) ? kr : 128;
        if (jc < lim) s += bf2f(gv & 0xffffu) * cv.x;
        if (jc + 1 < lim) s += bf2f(gv >> 16) * cv.y;
      }
      s = wave_reduce(s);
      if (lane == 0) store_wt(&c1[gw], ETA / (1.f + __expf(p_k + s)));
    }
    grid_barrier(flags, release, ++gen, wg, tid);

    // ---- Phase C: theta_{b+1}[d] = theta_b[d] + sum_k c1[k] xb[k][d]
    // 64 active WGs; WG wg owns d-slice [wg*32, wg*32+32) = one 64B line per
    // row -> coalesced, zero over-fetch, single-writer.
    if (wg < 64) {
#pragma unroll
      for (int i = 0; i < 4; i++) c1s[i * 256 + tid] = c1[i * 256 + tid];
      __syncthreads();
      int d0 = wg * 32;
      const short* xp =
          xb + (size_t)(b * B_BLK) * D_DIM + d0 + (lane & 3) * 8;
      float a8[8] = {0.f, 0.f, 0.f, 0.f, 0.f, 0.f, 0.f, 0.f};
      int rbase = wid * 256 + (lane >> 2);
      for (int i = 0; i < 16; i++) {
        int row = rbase + i * 16;
        short8_t xv = *(const short8_t*)(xp + (size_t)row * D_DIM);
        float c = c1s[row];
#pragma unroll
        for (int jj = 0; jj < 8; jj++) a8[jj] += c * bf2f((uint16_t)xv[jj]);
      }
      // reduce across the 16 lanes sharing (lane&3)
#pragma unroll
      for (int off = 4; off < 64; off <<= 1)
#pragma unroll
        for (int jj = 0; jj < 8; jj++) a8[jj] += __shfl_xor(a8[jj], off, 64);
      if (lane < 4) {
#pragma unroll
        for (int jj = 0; jj < 8; jj++) redc[wid][lane][jj] = a8[jj];
      }
      __syncthreads();
      if (tid < 32) {
        int oct = tid >> 3, e = tid & 7;
        float tot = redc[0][oct][e] + redc[1][oct][e] + redc[2][oct][e] +
                    redc[3][oct][e];
        store_wt(&theta_arr[(size_t)(b + 1) * D_DIM + d0 + tid],
                 theta[d0 + tid] + tot);
      }
    }
    if (b < N_BLK - 1) grid_barrier(flags, release, ++gen, wg, tid);
  }
}

// ---------------------------------------------------------------------------
extern "C" void kernel_launch(void* const* d_in, const int* in_sizes, int n_in,
                              void* d_out, int out_size, void* d_ws,
                              size_t ws_size, hipStream_t stream) {
  const float* theta_in = (const float*)d_in[0];  // (2048,)
  const float* xs = (const float*)d_in[1];        // (16384, 2048) fp32

  char* ws = (char*)d_ws;
  const size_t XB_BYTES = (size_t)N_STEPS * D_DIM * sizeof(short);  // 64MB
  const size_t G_BYTES = (size_t)N_BLK * N_TILE * 128 * 128 * sizeof(short);
  short* xb = (short*)ws;
  short* G = (short*)(ws + XB_BYTES);
  float* theta_arr = (float*)(ws + XB_BYTES + G_BYTES);  // (N_BLK+1) x 2048
  float* c0_arr = theta_arr + (size_t)(N_BLK + 1) * D_DIM;
  float* c1_arr = c0_arr + (size_t)N_BLK * B_BLK;
  int* flags = (int*)(c1_arr + (size_t)N_BLK * B_BLK);
  int* release = flags + NWG * FLAG_STRIDE;

  hipMemsetAsync(flags, 0, (NWG * FLAG_STRIDE + 16) * sizeof(int), stream);
  hipMemcpyAsync(theta_arr, theta_in, D_DIM * sizeof(float),
                 hipMemcpyDeviceToDevice, stream);

  cast_kernel<<<(N_STEPS * D_DIM / 8) / 256, 256, 0, stream>>>(xs, xb);
  gram_kernel<<<N_BLK * N_TILE, 256, 0, stream>>>(xb, G);
  solve_kernel<<<NWG, 256, 0, stream>>>(xb, G, theta_arr, c0_arr, c1_arr,
                                        flags, release);

  hipMemcpyAsync(d_out, theta_arr + (size_t)N_BLK * D_DIM,
                 D_DIM * sizeof(float), hipMemcpyDeviceToDevice, stream);
}